// Round 7
// baseline (470.197 us; speedup 1.0000x reference)
//
#include <hip/hip_runtime.h>

#define DEVINL __device__ __forceinline__

typedef __attribute__((ext_vector_type(8))) short short8;
typedef __attribute__((ext_vector_type(4))) short sh4;
typedef __attribute__((ext_vector_type(4))) float floatx4;

constexpr int S_LEN = 2048;
constexpr int DM    = 1024;
constexpr int NHEAD = 16;
constexpr int DHEAD = 64;
constexpr int BATCH = 2;
constexpr int MROWS = BATCH * S_LEN; // 4096
constexpr float LOG2E = 1.44269504f;
// fixed-max softmax: p = exp2(s_raw*0.125*LOG2E - 24*LOG2E); normalization cancels in O/l.
constexpr float SM_C1 = 0.125f * LOG2E;
constexpr float SM_C2 = -24.0f * LOG2E;

// 16x16x16 bf16 MFMA (A/B = 4 bf16 = 2 VGPR). No __has_builtin guard — amdgcn
// builtins are aux-target in the host pass (guard returns false there).
#define MFMA16(a, b, c) __builtin_amdgcn_mfma_f32_16x16x16bf16_1k(a, b, c, 0, 0, 0)

DEVINL unsigned short f2bf(float x) {  // RNE
  union { float f; unsigned u; } un; un.f = x;
  unsigned u = un.u;
  return (unsigned short)((u + 0x7fffu + ((u >> 16) & 1u)) >> 16);
}
DEVINL unsigned short f2bf_fast(float x) {  // round-half-up (x >= 0)
  union { float f; unsigned u; } un; un.f = x;
  return (unsigned short)((un.u + 0x8000u) >> 16);
}

// ---------------- prep: fp32->bf16 convert (3 tensors) + weight transpose (4) ----------------
__global__ __launch_bounds__(256) void prep_kernel(const float* __restrict__ s0,
                                                   const float* __restrict__ s1,
                                                   const float* __restrict__ s2,
                                                   unsigned short* __restrict__ d0,
                                                   unsigned short* __restrict__ d1,
                                                   unsigned short* __restrict__ d2,
                                                   const float* __restrict__ W0,
                                                   const float* __restrict__ W1,
                                                   const float* __restrict__ W2,
                                                   const float* __restrict__ W3,
                                                   unsigned short* __restrict__ T0,
                                                   unsigned short* __restrict__ T1,
                                                   unsigned short* __restrict__ T2,
                                                   unsigned short* __restrict__ T3) {
  __shared__ unsigned short tile[32][33];
  const int y = blockIdx.y;
  if (y < 3) {
    const float* s = y == 0 ? s0 : (y == 1 ? s1 : s2);
    unsigned short* d = y == 0 ? d0 : (y == 1 ? d1 : d2);
    int i = (blockIdx.x * 256 + threadIdx.x) * 4;
    float4 v = *(const float4*)(s + i);
    unsigned lo = (unsigned)f2bf(v.x) | ((unsigned)f2bf(v.y) << 16);
    unsigned hi = (unsigned)f2bf(v.z) | ((unsigned)f2bf(v.w) << 16);
    *(uint2*)(d + i) = make_uint2(lo, hi);
  } else {
    const int x = blockIdx.x;
    const int wsel = x >> 10, rem = x & 1023;
    const float* W = wsel == 0 ? W0 : (wsel == 1 ? W1 : (wsel == 2 ? W2 : W3));
    unsigned short* Wt = wsel == 0 ? T0 : (wsel == 1 ? T1 : (wsel == 2 ? T2 : T3));
    int t = threadIdx.x;
    int c = t & 31, r0 = t >> 5;
    int nB = (rem & 31) * 32, kB = (rem >> 5) * 32;
    for (int i = 0; i < 4; ++i) {
      int r = r0 + i * 8;
      tile[r][c] = f2bf(W[(size_t)(kB + r) * DM + nB + c]);
    }
    __syncthreads();
    for (int i = 0; i < 4; ++i) {
      int r = r0 + i * 8;
      Wt[(size_t)(nB + r) * DM + kB + c] = tile[c][r];
    }
  }
}

// ------------- async 16B global->LDS -------------
DEVINL void load_lds16(const unsigned short* g, unsigned short* l) {
  __builtin_amdgcn_global_load_lds((const __attribute__((address_space(1))) unsigned int*)g,
                                   (__attribute__((address_space(3))) unsigned int*)l,
                                   16, 0, 0);
}

// ------------- GEMM body (128x128 tile): C = A[4096][1024] @ Bt^T -------------
// MODE 0: bf16 row-major out; MODE 2: bf16 V-transposed out
// (vt[(b*16+h)*64+d][s], fusing the V-transpose into the V projection).
template <int MODE>
DEVINL void gemm_body(const unsigned short* __restrict__ A,
                      const unsigned short* __restrict__ Bt,
                      void* __restrict__ Cout) {
  constexpr int K = 1024, N = 1024;
  __shared__ alignas(16) unsigned short As[128 * 32];
  __shared__ alignas(16) unsigned short Bs[128 * 32];
  const int tid  = threadIdx.x;
  const int wave = tid >> 6, lane = tid & 63;
  const int quad = lane >> 4, l16 = lane & 15;
  const int mBase = blockIdx.y * 128, nBase = blockIdx.x * 128;
  const int wm = (wave >> 1) * 64, wn = (wave & 1) * 64;
  const int sr = lane >> 2;
  const int sc = (lane & 3) * 8;
  floatx4 acc[4][4] = {};

  for (int k0 = 0; k0 < K; k0 += 32) {
    __syncthreads();
#pragma unroll
    for (int j = 0; j < 2; ++j) {
      int row = wave * 32 + j * 16 + sr;
      load_lds16(A  + (size_t)(mBase + row) * K + k0 + sc, As + (wave * 32 + j * 16) * 32);
      load_lds16(Bt + (size_t)(nBase + row) * K + k0 + sc, Bs + (wave * 32 + j * 16) * 32);
    }
    __syncthreads();
    short8 af[4], bfr[4];
#pragma unroll
    for (int mt = 0; mt < 4; ++mt) af[mt]  = *(const short8*)&As[(wm + mt * 16 + l16) * 32 + quad * 8];
#pragma unroll
    for (int nt = 0; nt < 4; ++nt) bfr[nt] = *(const short8*)&Bs[(wn + nt * 16 + l16) * 32 + quad * 8];
#pragma unroll
    for (int mt = 0; mt < 4; ++mt)
#pragma unroll
      for (int nt = 0; nt < 4; ++nt)
        acc[mt][nt] = __builtin_amdgcn_mfma_f32_16x16x32_bf16(af[mt], bfr[nt], acc[mt][nt], 0, 0, 0);
  }

#pragma unroll
  for (int mt = 0; mt < 4; ++mt)
#pragma unroll
    for (int nt = 0; nt < 4; ++nt) {
      const int m = mBase + wm + mt * 16 + quad * 4;   // +r
      const int n = nBase + wn + nt * 16 + l16;
      if (MODE == 2) {
        const int bq = m >> 11, s = m & 2047;
        const int hh = n >> 6,  d = n & 63;
        unsigned short w4[4];
#pragma unroll
        for (int r = 0; r < 4; ++r) w4[r] = f2bf(acc[mt][nt][r]);
        *(uint2*)&((unsigned short*)Cout)[((size_t)((bq * 16 + hh) * 64 + d)) * S_LEN + s] =
            *(const uint2*)w4;
      } else {
#pragma unroll
        for (int r = 0; r < 4; ++r)
          ((unsigned short*)Cout)[(size_t)(m + r) * N + n] = f2bf(acc[mt][nt][r]);
      }
    }
}

__global__ __launch_bounds__(256) void gemm_qkv(const unsigned short* __restrict__ A0,
                                                const unsigned short* __restrict__ A1,
                                                const unsigned short* __restrict__ A2,
                                                const unsigned short* __restrict__ B0,
                                                const unsigned short* __restrict__ B1,
                                                const unsigned short* __restrict__ B2,
                                                unsigned short* __restrict__ C0,
                                                unsigned short* __restrict__ C1,
                                                unsigned short* __restrict__ C2) {
  const int z = blockIdx.z;
  if (z == 2)      gemm_body<2>(A2, B2, C2);   // V: write transposed vt directly
  else if (z == 1) gemm_body<0>(A1, B1, C1);
  else             gemm_body<0>(A0, B0, C0);
}

// ------------- output GEMM, 64x128 tile (512 blocks -> 2/CU overlap) -------------
__global__ __launch_bounds__(256) void gemm_out64(const unsigned short* __restrict__ A,
                                                  const unsigned short* __restrict__ Bt,
                                                  float* __restrict__ C) {
  constexpr int K = 1024, N = 1024;
  __shared__ alignas(16) unsigned short As[64 * 32];
  __shared__ alignas(16) unsigned short Bs[128 * 32];
  const int tid  = threadIdx.x;
  const int wave = tid >> 6, lane = tid & 63;
  const int quad = lane >> 4, l16 = lane & 15;
  const int mBase = blockIdx.y * 64, nBase = blockIdx.x * 128;
  const int wm = (wave >> 1) * 32, wn = (wave & 1) * 64;
  const int sr = lane >> 2;
  const int sc = (lane & 3) * 8;
  floatx4 acc[2][4] = {};

  for (int k0 = 0; k0 < K; k0 += 32) {
    __syncthreads();
    load_lds16(A + (size_t)(mBase + wave * 16 + sr) * K + k0 + sc, As + (wave * 16) * 32);
#pragma unroll
    for (int j = 0; j < 2; ++j) {
      int row = wave * 32 + j * 16 + sr;
      load_lds16(Bt + (size_t)(nBase + row) * K + k0 + sc, Bs + (wave * 32 + j * 16) * 32);
    }
    __syncthreads();
    short8 af[2], bfr[4];
#pragma unroll
    for (int mt = 0; mt < 2; ++mt) af[mt]  = *(const short8*)&As[(wm + mt * 16 + l16) * 32 + quad * 8];
#pragma unroll
    for (int nt = 0; nt < 4; ++nt) bfr[nt] = *(const short8*)&Bs[(wn + nt * 16 + l16) * 32 + quad * 8];
#pragma unroll
    for (int mt = 0; mt < 2; ++mt)
#pragma unroll
      for (int nt = 0; nt < 4; ++nt)
        acc[mt][nt] = __builtin_amdgcn_mfma_f32_16x16x32_bf16(af[mt], bfr[nt], acc[mt][nt], 0, 0, 0);
  }

#pragma unroll
  for (int mt = 0; mt < 2; ++mt)
#pragma unroll
    for (int nt = 0; nt < 4; ++nt)
#pragma unroll
      for (int r = 0; r < 4; ++r) {
        int m = mBase + wm + mt * 16 + quad * 4 + r;
        int n = nBase + wn + nt * 16 + l16;
        C[(size_t)m * N + n] = acc[mt][nt][r];
      }
}

// ------------- causal flash attention: 8-wave blocks, DMA-staged dbuf K/V, register P ----
// S^T trick: QK as A=K,B=Q -> lane holds P[q=l16][s=quad*4+r] = A-operand layout of
// mfma 16x16x16 for PV -> P never leaves registers.
//
// R14/R15: 8-WAVE (512-thread) blocks for 2x occupancy. R13's 4-wave blocks
// capped the CU at 2 blocks x 4 waves = 8 waves (25%); VALUBusy stalled at ~49%
// with only 2 waves/SIMD to hide MFMA deps + quarter-rate exp2.
// Wave w = (qgrp = w>>2, sgrp = w&3): sgrp = s-strip of the KV tile (as before),
// qgrp = which half of the 4 q-subtiles this wave computes (2 each). 512 blocks
// of 8 waves -> 2 blocks/CU -> 16 waves/CU (4/SIMD).
//   * LDS arena 42KB: epilogue buffers ALIASED onto the KV double-buffer. Safe:
//     DMA issue is guarded (t+1<nT), so nothing is in flight at the epilogue;
//     each half opens with barrier + fresh tile-0 stage (one exposed DMA/half).
//   * staging spread over 8 waves (2 x load_lds16 per thread).
//   * epilogue: 2 merge rounds (one per qgrp's nt), 4 s-strip partials each.
// R13: explicit s_waitcnt vmcnt(0) before each in-loop barrier (the barrier alone
// does NOT order vmcnt-tracked LDS-DMA — R12 raced; R11's implicit wait was the
// slow version). Read fragments FIRST after the barrier, then issue next DMA.
// XOR swizzle chunk^=(row&7): DMA dest lane-linear, global source pre-swizzled,
// reads apply the same XOR. R9: block x handles pair (31-x, x) => uniform 33 steps.
__global__ __launch_bounds__(512, 4) void attn_kernel(const unsigned short* __restrict__ Qp,
                                                      const unsigned short* __restrict__ Kp,
                                                      const unsigned short* __restrict__ Vtg,
                                                      unsigned short* __restrict__ ctx) {
  const int bh = blockIdx.y;
  const int b  = bh >> 4, h = bh & 15;
  const int tid = threadIdx.x;
  const int w = tid >> 6, lane = tid & 63;
  const int quad = lane >> 4, l16 = lane & 15;
  const int sgrp = w & 3, qgrp = w >> 2;

  // LDS arena: [0,32768) = KVs 2 buffers x (K 4096 | V 4096 shorts);
  // epilogue aliases: Ored [2][4][4][16][20] f32 @0 (40960B), rsL [8][2][16] f32 @40960.
  __shared__ alignas(16) char smem[41984];
  unsigned short* KVs = (unsigned short*)smem;
  float* OredB = (float*)smem;
  float* rsLB  = (float*)(smem + 40960);

  const unsigned short* Kbh = Kp  + (size_t)(b * S_LEN) * DM + h * DHEAD;
  const unsigned short* Vbh = Vtg + (size_t)(bh * DHEAD) * S_LEN;

  // ---- DMA staging geometry: 1024 16B-chunks (512 K + 512 V), 2 per thread ----
  // wave w<4 stages K chunks p = (w&3)*128 + j*64 + lane; w>=4 same for V.
  // LDS slot linear in p; global source chunk = (p&7)^(row&7)  (read-side XOR matches).
  const bool stageK = (w < 4);
  const int vbase = stageK ? 0 : 4096;      // shorts, within a buffer
  int srow[2], scol[2];
#pragma unroll
  for (int j = 0; j < 2; ++j) {
    const int p = sgrp * 128 + j * 64 + lane;
    srow[j] = p >> 3;
    scol[j] = ((p & 7) ^ (srow[j] & 7)) * 8;
  }
  const int dstOff = vbase + sgrp * 1024;   // + j*512, lane-linear via DMA

  // ---- swizzled read addresses (within a buffer, shorts) ----
  const int swz = l16 & 7;
  const int kRow = (sgrp * 16 + l16) * 64;
  const int kOff0 = kRow + ((0 + quad) ^ swz) * 8;       // K chunks quad, 4+quad
  const int kOff1 = kRow + ((4 + quad) ^ swz) * 8;
  int vOff[4];
#pragma unroll
  for (int dt = 0; dt < 4; ++dt) {
    const int ch = 2 * sgrp + (quad >> 1);
    vOff[dt] = 4096 + (dt * 16 + l16) * 64 + (ch ^ swz) * 8 + (quad & 1) * 4;
  }

#pragma unroll 1
  for (int half = 0; half < 2; ++half) {
    const int qt = half ? (int)blockIdx.x : 31 - (int)blockIdx.x;  // heavy tile first
    const int Q0 = qt * 64;
    const int nT = qt + 1;

    // all waves done with the aliased epilogue region before restaging KVs
    __syncthreads();
    int cur = 0;
    {  // stage tile 0 into buffer 0
      unsigned short* dst = KVs + dstOff;
#pragma unroll
      for (int j = 0; j < 2; ++j) {
        const unsigned short* src = stageK
            ? Kbh + (size_t)srow[j] * DM + scol[j]
            : Vbh + (size_t)srow[j] * S_LEN + scol[j];
        load_lds16(src, dst + j * 512);
      }
    }

    // Q fragments for this wave's 2 q-subtiles (B-operand: n=l16 -> q, k=quad*8+j -> d)
    short8 qB[2][2];
#pragma unroll
    for (int ntl = 0; ntl < 2; ++ntl) {
      const int nt = qgrp * 2 + ntl;
      const size_t qr = ((size_t)(b * S_LEN + Q0 + nt * 16 + l16)) * DM + h * DHEAD + quad * 8;
      qB[ntl][0] = *(const short8*)&Qp[qr];
      qB[ntl][1] = *(const short8*)&Qp[qr + 32];
    }

    floatx4 o[2][4] = {};
    float rs[2] = {0.f, 0.f};

#pragma unroll 1
    for (int t = 0; t < nT; ++t) {
      // drain own DMA (issued a compute-phase ago except t=0), publish via barrier.
      asm volatile("s_waitcnt vmcnt(0)" ::: "memory");
      __syncthreads();

      // fragments from LDS (swizzled) FIRST — nothing outstanding can stall them.
      const unsigned short* buf = KVs + cur * 8192;
      short8 kc0 = *(const short8*)&buf[kOff0];
      short8 kc1 = *(const short8*)&buf[kOff1];
      sh4 vv[4];
#pragma unroll
      for (int dt = 0; dt < 4; ++dt) vv[dt] = *(const sh4*)&buf[vOff[dt]];

      // THEN issue DMA for the NEXT tile (guarded: nothing in flight at epilogue,
      // required for the LDS alias). Overlaps this step's compute.
      if (t + 1 < nT) {
        const int kb = (t + 1) * 64;
        unsigned short* dst = KVs + (cur ^ 1) * 8192 + dstOff;
#pragma unroll
        for (int j = 0; j < 2; ++j) {
          const unsigned short* src = stageK
              ? Kbh + (size_t)(kb + srow[j]) * DM + scol[j]
              : Vbh + (size_t)srow[j] * S_LEN + kb + scol[j];
          load_lds16(src, dst + j * 512);
        }
      }

      const bool masked = (t == nT - 1);
      const int sbase = sgrp * 16 + quad * 4;   // s - kb, + r

#pragma unroll
      for (int ntl = 0; ntl < 2; ++ntl) {
        const int nt = qgrp * 2 + ntl;
        floatx4 sc = {};
        sc = __builtin_amdgcn_mfma_f32_16x16x32_bf16(kc0, qB[ntl][0], sc, 0, 0, 0);
        sc = __builtin_amdgcn_mfma_f32_16x16x32_bf16(kc1, qB[ntl][1], sc, 0, 0, 0);
        const int qoff = nt * 16 + l16;      // q - Q0
        sh4 pa;
        float acc = 0.f;
#pragma unroll
        for (int r = 0; r < 4; ++r) {
          float p = __builtin_amdgcn_exp2f(fmaf(sc[r], SM_C1, SM_C2));
          if (masked && (sbase + r > qoff)) p = 0.f;
          acc += p;
          pa[r] = (short)f2bf_fast(p);
        }
        rs[ntl] += acc;
#pragma unroll
        for (int dt = 0; dt < 4; ++dt)
          o[ntl][dt] = MFMA16(pa, vv[dt], o[ntl][dt]);
      }

      cur ^= 1;
    }

    // ---- epilogue: merge 4 s-strip partials per qgrp, normalize, write ctx ----
#pragma unroll
    for (int ntl = 0; ntl < 2; ++ntl) {
      rs[ntl] += __shfl_xor(rs[ntl], 16, 64);
      rs[ntl] += __shfl_xor(rs[ntl], 32, 64);
    }
    if (quad == 0) {
#pragma unroll
      for (int ntl = 0; ntl < 2; ++ntl) rsLB[(w * 2 + ntl) * 16 + l16] = rs[ntl];
    }

#pragma unroll 1
    for (int ntl = 0; ntl < 2; ++ntl) {
      const int nt = qgrp * 2 + ntl;
      __syncthreads();   // round 0: also guards "all KVs reads done" for the alias
#pragma unroll
      for (int dt = 0; dt < 4; ++dt)
        *(floatx4*)&OredB[((((qgrp * 4 + sgrp) * 4 + dt) * 16 + l16) * 20) + quad * 4] =
            o[ntl][dt];
      __syncthreads();
      // wave (qgrp,sgrp) merges d-tile dt == sgrp of its group's nt
      floatx4 acc = {};
#pragma unroll
      for (int s2 = 0; s2 < 4; ++s2) {
        floatx4 v = *(const floatx4*)&OredB[((((qgrp * 4 + s2) * 4 + sgrp) * 16 + l16) * 20) + quad * 4];
#pragma unroll
        for (int j = 0; j < 4; ++j) acc[j] += v[j];
      }
#pragma unroll
      for (int j = 0; j < 4; ++j) {
        const int q16 = quad * 4 + j;
        float l = rsLB[((qgrp * 4 + 0) * 2 + ntl) * 16 + q16] +
                  rsLB[((qgrp * 4 + 1) * 2 + ntl) * 16 + q16] +
                  rsLB[((qgrp * 4 + 2) * 2 + ntl) * 16 + q16] +
                  rsLB[((qgrp * 4 + 3) * 2 + ntl) * 16 + q16];
        const size_t row = (size_t)(b * S_LEN + Q0 + nt * 16 + q16);
        ctx[row * DM + h * DHEAD + sgrp * 16 + l16] = f2bf(acc[j] / l);
      }
    }
  }
}

extern "C" void kernel_launch(void* const* d_in, const int* in_sizes, int n_in,
                              void* d_out, int out_size, void* d_ws, size_t ws_size,
                              hipStream_t stream) {
  const float* Xq = (const float*)d_in[0];
  const float* Xk = (const float*)d_in[1];
  const float* Xv = (const float*)d_in[2];
  const float* Wq = (const float*)d_in[5];
  const float* Wk = (const float*)d_in[6];
  const float* Wv = (const float*)d_in[7];
  const float* Wo = (const float*)d_in[8];
  float* out = (float*)d_out;

  char* ws = (char*)d_ws;
  constexpr size_t XBYTES = (size_t)MROWS * DM * 2;  // 8 MiB
  constexpr size_t WBYTES = (size_t)DM * DM * 2;     // 2 MiB
  unsigned short* xq_bf = (unsigned short*)(ws);
  unsigned short* xk_bf = (unsigned short*)(ws + XBYTES);
  unsigned short* xv_bf = (unsigned short*)(ws + 2 * XBYTES);
  unsigned short* wqt   = (unsigned short*)(ws + 3 * XBYTES);
  unsigned short* wkt   = (unsigned short*)(ws + 3 * XBYTES + WBYTES);
  unsigned short* wvt   = (unsigned short*)(ws + 3 * XBYTES + 2 * WBYTES);
  unsigned short* wot   = (unsigned short*)(ws + 3 * XBYTES + 3 * WBYTES);
  unsigned short* qp    = (unsigned short*)(ws + 3 * XBYTES + 4 * WBYTES);
  unsigned short* kp    = (unsigned short*)(ws + 4 * XBYTES + 4 * WBYTES);
  unsigned short* vt    = (unsigned short*)(ws + 5 * XBYTES + 4 * WBYTES); // V^T, written by V-GEMM
  unsigned short* ctx   = xq_bf;  // dead after Q projection

  // fused prep: y=0..2 convert Xq/Xk/Xv; y=3 transpose the 4 weights
  prep_kernel<<<dim3(4096, 4), 256, 0, stream>>>(Xq, Xk, Xv, xq_bf, xk_bf, xv_bf,
                                                 Wq, Wk, Wv, Wo, wqt, wkt, wvt, wot);

  gemm_qkv<<<dim3(DM / 128, MROWS / 128, 3), 256, 0, stream>>>(
      xq_bf, xk_bf, xv_bf, wqt, wkt, wvt, qp, kp, vt);

  // paired causal schedule: block x handles q-tiles (31-x, x) => uniform 33 steps.
  // 512 blocks x 8 waves = 2 blocks/CU = 16 waves/CU.
  attn_kernel<<<dim3(16, BATCH * NHEAD), 512, 0, stream>>>(qp, kp, vt, ctx);

  gemm_out64<<<dim3(DM / 128, MROWS / 64), 256, 0, stream>>>(ctx, wot, out);
}

// Round 8
// 229.650 us; speedup vs baseline: 2.0474x; 2.0474x over previous
//
#include <hip/hip_runtime.h>

#define DEVINL __device__ __forceinline__

typedef __attribute__((ext_vector_type(8))) short short8;
typedef __attribute__((ext_vector_type(4))) short sh4;
typedef __attribute__((ext_vector_type(4))) float floatx4;

constexpr int S_LEN = 2048;
constexpr int DM    = 1024;
constexpr int NHEAD = 16;
constexpr int DHEAD = 64;
constexpr int BATCH = 2;
constexpr int MROWS = BATCH * S_LEN; // 4096
constexpr float LOG2E = 1.44269504f;
// fixed-max softmax: p = exp2(s_raw*0.125*LOG2E - 24*LOG2E); normalization cancels in O/l.
constexpr float SM_C1 = 0.125f * LOG2E;
constexpr float SM_C2 = -24.0f * LOG2E;

// 16x16x16 bf16 MFMA (A/B = 4 bf16 = 2 VGPR). No __has_builtin guard — amdgcn
// builtins are aux-target in the host pass (guard returns false there).
#define MFMA16(a, b, c) __builtin_amdgcn_mfma_f32_16x16x16bf16_1k(a, b, c, 0, 0, 0)

DEVINL unsigned short f2bf(float x) {  // RNE
  union { float f; unsigned u; } un; un.f = x;
  unsigned u = un.u;
  return (unsigned short)((u + 0x7fffu + ((u >> 16) & 1u)) >> 16);
}
DEVINL unsigned short f2bf_fast(float x) {  // round-half-up (x >= 0)
  union { float f; unsigned u; } un; un.f = x;
  return (unsigned short)((un.u + 0x8000u) >> 16);
}

// ---------------- prep: fp32->bf16 convert (3 tensors) + weight transpose (4) ----------------
__global__ __launch_bounds__(256) void prep_kernel(const float* __restrict__ s0,
                                                   const float* __restrict__ s1,
                                                   const float* __restrict__ s2,
                                                   unsigned short* __restrict__ d0,
                                                   unsigned short* __restrict__ d1,
                                                   unsigned short* __restrict__ d2,
                                                   const float* __restrict__ W0,
                                                   const float* __restrict__ W1,
                                                   const float* __restrict__ W2,
                                                   const float* __restrict__ W3,
                                                   unsigned short* __restrict__ T0,
                                                   unsigned short* __restrict__ T1,
                                                   unsigned short* __restrict__ T2,
                                                   unsigned short* __restrict__ T3) {
  __shared__ unsigned short tile[32][33];
  const int y = blockIdx.y;
  if (y < 3) {
    const float* s = y == 0 ? s0 : (y == 1 ? s1 : s2);
    unsigned short* d = y == 0 ? d0 : (y == 1 ? d1 : d2);
    int i = (blockIdx.x * 256 + threadIdx.x) * 4;
    float4 v = *(const float4*)(s + i);
    unsigned lo = (unsigned)f2bf(v.x) | ((unsigned)f2bf(v.y) << 16);
    unsigned hi = (unsigned)f2bf(v.z) | ((unsigned)f2bf(v.w) << 16);
    *(uint2*)(d + i) = make_uint2(lo, hi);
  } else {
    const int x = blockIdx.x;
    const int wsel = x >> 10, rem = x & 1023;
    const float* W = wsel == 0 ? W0 : (wsel == 1 ? W1 : (wsel == 2 ? W2 : W3));
    unsigned short* Wt = wsel == 0 ? T0 : (wsel == 1 ? T1 : (wsel == 2 ? T2 : T3));
    int t = threadIdx.x;
    int c = t & 31, r0 = t >> 5;
    int nB = (rem & 31) * 32, kB = (rem >> 5) * 32;
    for (int i = 0; i < 4; ++i) {
      int r = r0 + i * 8;
      tile[r][c] = f2bf(W[(size_t)(kB + r) * DM + nB + c]);
    }
    __syncthreads();
    for (int i = 0; i < 4; ++i) {
      int r = r0 + i * 8;
      Wt[(size_t)(nB + r) * DM + kB + c] = tile[c][r];
    }
  }
}

// ------------- async 16B global->LDS -------------
DEVINL void load_lds16(const unsigned short* g, unsigned short* l) {
  __builtin_amdgcn_global_load_lds((const __attribute__((address_space(1))) unsigned int*)g,
                                   (__attribute__((address_space(3))) unsigned int*)l,
                                   16, 0, 0);
}

// ------------- GEMM body (128x128 tile): C = A[4096][1024] @ Bt^T -------------
// MODE 0: bf16 row-major out; MODE 2: bf16 V-transposed out
// (vt[(b*16+h)*64+d][s], fusing the V-transpose into the V projection).
template <int MODE>
DEVINL void gemm_body(const unsigned short* __restrict__ A,
                      const unsigned short* __restrict__ Bt,
                      void* __restrict__ Cout) {
  constexpr int K = 1024, N = 1024;
  __shared__ alignas(16) unsigned short As[128 * 32];
  __shared__ alignas(16) unsigned short Bs[128 * 32];
  const int tid  = threadIdx.x;
  const int wave = tid >> 6, lane = tid & 63;
  const int quad = lane >> 4, l16 = lane & 15;
  const int mBase = blockIdx.y * 128, nBase = blockIdx.x * 128;
  const int wm = (wave >> 1) * 64, wn = (wave & 1) * 64;
  const int sr = lane >> 2;
  const int sc = (lane & 3) * 8;
  floatx4 acc[4][4] = {};

  for (int k0 = 0; k0 < K; k0 += 32) {
    __syncthreads();
#pragma unroll
    for (int j = 0; j < 2; ++j) {
      int row = wave * 32 + j * 16 + sr;
      load_lds16(A  + (size_t)(mBase + row) * K + k0 + sc, As + (wave * 32 + j * 16) * 32);
      load_lds16(Bt + (size_t)(nBase + row) * K + k0 + sc, Bs + (wave * 32 + j * 16) * 32);
    }
    __syncthreads();
    short8 af[4], bfr[4];
#pragma unroll
    for (int mt = 0; mt < 4; ++mt) af[mt]  = *(const short8*)&As[(wm + mt * 16 + l16) * 32 + quad * 8];
#pragma unroll
    for (int nt = 0; nt < 4; ++nt) bfr[nt] = *(const short8*)&Bs[(wn + nt * 16 + l16) * 32 + quad * 8];
#pragma unroll
    for (int mt = 0; mt < 4; ++mt)
#pragma unroll
      for (int nt = 0; nt < 4; ++nt)
        acc[mt][nt] = __builtin_amdgcn_mfma_f32_16x16x32_bf16(af[mt], bfr[nt], acc[mt][nt], 0, 0, 0);
  }

#pragma unroll
  for (int mt = 0; mt < 4; ++mt)
#pragma unroll
    for (int nt = 0; nt < 4; ++nt) {
      const int m = mBase + wm + mt * 16 + quad * 4;   // +r
      const int n = nBase + wn + nt * 16 + l16;
      if (MODE == 2) {
        const int bq = m >> 11, s = m & 2047;
        const int hh = n >> 6,  d = n & 63;
        unsigned short w4[4];
#pragma unroll
        for (int r = 0; r < 4; ++r) w4[r] = f2bf(acc[mt][nt][r]);
        *(uint2*)&((unsigned short*)Cout)[((size_t)((bq * 16 + hh) * 64 + d)) * S_LEN + s] =
            *(const uint2*)w4;
      } else {
#pragma unroll
        for (int r = 0; r < 4; ++r)
          ((unsigned short*)Cout)[(size_t)(m + r) * N + n] = f2bf(acc[mt][nt][r]);
      }
    }
}

__global__ __launch_bounds__(256) void gemm_qkv(const unsigned short* __restrict__ A0,
                                                const unsigned short* __restrict__ A1,
                                                const unsigned short* __restrict__ A2,
                                                const unsigned short* __restrict__ B0,
                                                const unsigned short* __restrict__ B1,
                                                const unsigned short* __restrict__ B2,
                                                unsigned short* __restrict__ C0,
                                                unsigned short* __restrict__ C1,
                                                unsigned short* __restrict__ C2) {
  const int z = blockIdx.z;
  if (z == 2)      gemm_body<2>(A2, B2, C2);   // V: write transposed vt directly
  else if (z == 1) gemm_body<0>(A1, B1, C1);
  else             gemm_body<0>(A0, B0, C0);
}

// ------------- output GEMM, 64x128 tile (512 blocks -> 2/CU overlap) -------------
__global__ __launch_bounds__(256) void gemm_out64(const unsigned short* __restrict__ A,
                                                  const unsigned short* __restrict__ Bt,
                                                  float* __restrict__ C) {
  constexpr int K = 1024, N = 1024;
  __shared__ alignas(16) unsigned short As[64 * 32];
  __shared__ alignas(16) unsigned short Bs[128 * 32];
  const int tid  = threadIdx.x;
  const int wave = tid >> 6, lane = tid & 63;
  const int quad = lane >> 4, l16 = lane & 15;
  const int mBase = blockIdx.y * 64, nBase = blockIdx.x * 128;
  const int wm = (wave >> 1) * 32, wn = (wave & 1) * 64;
  const int sr = lane >> 2;
  const int sc = (lane & 3) * 8;
  floatx4 acc[2][4] = {};

  for (int k0 = 0; k0 < K; k0 += 32) {
    __syncthreads();
    load_lds16(A + (size_t)(mBase + wave * 16 + sr) * K + k0 + sc, As + (wave * 16) * 32);
#pragma unroll
    for (int j = 0; j < 2; ++j) {
      int row = wave * 32 + j * 16 + sr;
      load_lds16(Bt + (size_t)(nBase + row) * K + k0 + sc, Bs + (wave * 32 + j * 16) * 32);
    }
    __syncthreads();
    short8 af[2], bfr[4];
#pragma unroll
    for (int mt = 0; mt < 2; ++mt) af[mt]  = *(const short8*)&As[(wm + mt * 16 + l16) * 32 + quad * 8];
#pragma unroll
    for (int nt = 0; nt < 4; ++nt) bfr[nt] = *(const short8*)&Bs[(wn + nt * 16 + l16) * 32 + quad * 8];
#pragma unroll
    for (int mt = 0; mt < 2; ++mt)
#pragma unroll
      for (int nt = 0; nt < 4; ++nt)
        acc[mt][nt] = __builtin_amdgcn_mfma_f32_16x16x32_bf16(af[mt], bfr[nt], acc[mt][nt], 0, 0, 0);
  }

#pragma unroll
  for (int mt = 0; mt < 2; ++mt)
#pragma unroll
    for (int nt = 0; nt < 4; ++nt)
#pragma unroll
      for (int r = 0; r < 4; ++r) {
        int m = mBase + wm + mt * 16 + quad * 4 + r;
        int n = nBase + wn + nt * 16 + l16;
        C[(size_t)m * N + n] = acc[mt][nt][r];
      }
}

// ------------- causal flash attention: DMA-staged double-buffered K/V, register P -------------
// S^T trick: QK as A=K,B=Q -> lane holds P[q=l16][s=quad*4+r] = A-operand layout of
// mfma 16x16x16 for PV -> P never leaves registers.
//
// R16 (this round): XCD-AWARE BLOCK REMAP on the proven R13 base (46.2us).
// R13's FETCH_SIZE was 96 MB vs ~24 MB working set: the 16 pair-blocks of each
// (b,h) — which all read the same 512 KB K/V — were round-robined across the
// 8 per-XCD L2s (linear id % 8), so every XCD re-fetched K/V from HBM, and the
// staging DMA saw ~900-cyc HBM latency > 1-step prefetch depth (~600 cyc).
// Remap (bijective): lin = y*16+x; xcd = lin&7; bh = (lin>>7)*8 + xcd;
// pair = (lin>>3)&15. All 16 blocks of a bh share one XCD; 4 bh x 512 KB = 2 MB
// fits the 4 MB L2/XCD; exactly 64 blocks/XCD — balance preserved.
// R15 lesson (reverted): 8-wave blocks under launch_bounds(512,4) spilled
// (VGPR_Count 40, WRITE_SIZE 1 GB scratch, 6x slower) — occupancy must not be
// bought with a 128-reg budget here.
// R13: explicit s_waitcnt vmcnt(0) before each in-loop barrier (barrier alone
// does NOT order vmcnt-tracked LDS-DMA — R12 raced). Read fragments FIRST after
// the barrier, then issue next DMA. XOR swizzle chunk^=(row&7) both-sides.
// R9: block handles complementary q-tile pair (31-p, p) => uniform 33 steps.
__global__ __launch_bounds__(256, 3) void attn_kernel(const unsigned short* __restrict__ Qp,
                                                      const unsigned short* __restrict__ Kp,
                                                      const unsigned short* __restrict__ Vtg,
                                                      unsigned short* __restrict__ ctx) {
  // ---- XCD-aware remap: keep all 16 pair-blocks of a bh on one XCD ----
  const int lin = (int)blockIdx.y * 16 + (int)blockIdx.x;   // dispatch linear id
  const int xcd = lin & 7;
  const int kk  = lin >> 3;              // 0..63
  const int bh  = ((kk >> 4) << 3) | xcd;  // 4 bh per XCD
  const int pairIdx = kk & 15;
  const int b  = bh >> 4, h = bh & 15;
  const int tid = threadIdx.x;
  const int w = tid >> 6, lane = tid & 63;
  const int quad = lane >> 4, l16 = lane & 15;

  // [2 buffers][K 4096 shorts | V 4096 shorts]; tile rows are 64 shorts (128B, 8 chunks)
  __shared__ alignas(16) unsigned short KVs[2 * 8192];
  __shared__ float rsL[4][4][16];                        // [wave][nt][q16]
  __shared__ alignas(16) float Ored[4][4][16][20];       // padded: 80B rows -> 2-way max

  const unsigned short* Kbh = Kp  + (size_t)(b * S_LEN) * DM + h * DHEAD;
  const unsigned short* Vbh = Vtg + (size_t)(bh * DHEAD) * S_LEN;

  // ---- DMA staging geometry: wave w stages segment w*4KB of the 16KB tile pair ----
  // chunk index p = (w&1)*256 + j*64 + lane; LDS gets linear chunks; global source
  // chunk is (p&7)^(row&7) so that LDS slot (row, c') holds global chunk c'^(row&7).
  int srow[4], scol[4];
#pragma unroll
  for (int j = 0; j < 4; ++j) {
    const int p = (w & 1) * 256 + j * 64 + lane;
    srow[j] = p >> 3;
    scol[j] = ((p & 7) ^ (srow[j] & 7)) * 8;
  }
  const bool stageK = (w < 2);

  // ---- swizzled read addresses (within a buffer, shorts) ----
  const int swz = l16 & 7;
  const int kRow = (w * 16 + l16) * 64;
  const int kOff0 = kRow + ((0 + quad) ^ swz) * 8;       // K chunks quad, 4+quad
  const int kOff1 = kRow + ((4 + quad) ^ swz) * 8;
  int vOff[4];
#pragma unroll
  for (int dt = 0; dt < 4; ++dt) {
    const int ch = 2 * w + (quad >> 1);
    vOff[dt] = 4096 + (dt * 16 + l16) * 64 + (ch ^ swz) * 8 + (quad & 1) * 4;
  }

  // issue DMA for tile 0 into buffer 0 (drained at the first in-loop waitcnt+barrier)
  {
    unsigned short* dst = KVs + w * 2048;
#pragma unroll
    for (int j = 0; j < 4; ++j) {
      const unsigned short* src = stageK
          ? Kbh + (size_t)srow[j] * DM + scol[j]
          : Vbh + (size_t)srow[j] * S_LEN + scol[j];
      load_lds16(src, dst + j * 512);
    }
  }

  int cur = 0;

#pragma unroll 1
  for (int half = 0; half < 2; ++half) {
    const int qt = half ? pairIdx : 31 - pairIdx;  // heavy tile first
    const int Q0 = qt * 64;
    const int nT = qt + 1;

    // Q fragments (B-operand: n=l16 -> q, k=quad*8+j -> d)
    short8 qB[4][2];
#pragma unroll
    for (int nt = 0; nt < 4; ++nt) {
      const size_t qr = ((size_t)(b * S_LEN + Q0 + nt * 16 + l16)) * DM + h * DHEAD + quad * 8;
      qB[nt][0] = *(const short8*)&Qp[qr];
      qB[nt][1] = *(const short8*)&Qp[qr + 32];
    }

    floatx4 o[4][4] = {};
    float rs[4] = {0.f, 0.f, 0.f, 0.f};

#pragma unroll 1
    for (int t = 0; t < nT; ++t) {
      // drain own DMA (issued a compute-phase ago -> ~no stall), then barrier
      // publishes the LDS writes to all waves. EXPLICIT because __syncthreads
      // alone does not order vmcnt-tracked LDS-DMA (R12 race).
      asm volatile("s_waitcnt vmcnt(0)" ::: "memory");
      __syncthreads();

      // fragments from LDS (swizzled) FIRST — nothing outstanding can stall
      // them; the may-alias DMA below cannot be hoisted above these reads.
      const unsigned short* buf = KVs + cur * 8192;
      short8 kc0 = *(const short8*)&buf[kOff0];
      short8 kc1 = *(const short8*)&buf[kOff1];
      sh4 vv[4];
#pragma unroll
      for (int dt = 0; dt < 4; ++dt) vv[dt] = *(const sh4*)&buf[vOff[dt]];

      // THEN issue DMA for the NEXT tile into the other buffer (tn=0 past the
      // end pre-warms tile 0 for the second q-tile); it overlaps this step's
      // compute and is drained at the next iteration's waitcnt.
      {
        const int tn = (t + 1 < nT) ? t + 1 : 0;
        const int kb = tn * 64;
        unsigned short* dst = KVs + (cur ^ 1) * 8192 + w * 2048;
#pragma unroll
        for (int j = 0; j < 4; ++j) {
          const unsigned short* src = stageK
              ? Kbh + (size_t)(kb + srow[j]) * DM + scol[j]
              : Vbh + (size_t)srow[j] * S_LEN + kb + scol[j];
          load_lds16(src, dst + j * 512);
        }
      }

      const bool masked = (t == nT - 1);
      const int sbase = w * 16 + quad * 4;   // s - kb, + r

#pragma unroll
      for (int nt = 0; nt < 4; ++nt) {
        floatx4 sc = {};
        sc = __builtin_amdgcn_mfma_f32_16x16x32_bf16(kc0, qB[nt][0], sc, 0, 0, 0);
        sc = __builtin_amdgcn_mfma_f32_16x16x32_bf16(kc1, qB[nt][1], sc, 0, 0, 0);
        const int qoff = nt * 16 + l16;      // q - Q0
        sh4 pa;
        float acc = 0.f;
#pragma unroll
        for (int r = 0; r < 4; ++r) {
          float p = __builtin_amdgcn_exp2f(fmaf(sc[r], SM_C1, SM_C2));
          if (masked && (sbase + r > qoff)) p = 0.f;
          acc += p;
          pa[r] = (short)f2bf_fast(p);
        }
        rs[nt] += acc;
#pragma unroll
        for (int dt = 0; dt < 4; ++dt)
          o[nt][dt] = MFMA16(pa, vv[dt], o[nt][dt]);
      }

      cur ^= 1;
    }

    // ---- epilogue: merge 4 wave-partials (additive), normalize, write ctx ----
    // (prewarm DMA for the next half stays in flight; it touches only KVs,
    // epilogue touches only Ored/rsL — drained at next half's first waitcnt)
#pragma unroll
    for (int nt = 0; nt < 4; ++nt) {
      rs[nt] += __shfl_xor(rs[nt], 16, 64);
      rs[nt] += __shfl_xor(rs[nt], 32, 64);
    }
    if (quad == 0) {
#pragma unroll
      for (int nt = 0; nt < 4; ++nt) rsL[w][nt][l16] = rs[nt];
    }

    for (int nt = 0; nt < 4; ++nt) {
      __syncthreads();
#pragma unroll
      for (int dt = 0; dt < 4; ++dt)
        *(floatx4*)&Ored[w][dt][l16][quad * 4] = o[nt][dt];
      __syncthreads();
      // wave w handles d-tile dt == w; lane -> (q = quad*4+j, d = w*16+l16)
      floatx4 acc = {};
#pragma unroll
      for (int w2 = 0; w2 < 4; ++w2) {
        floatx4 v = *(const floatx4*)&Ored[w2][w][l16][quad * 4];
#pragma unroll
        for (int j = 0; j < 4; ++j) acc[j] += v[j];
      }
#pragma unroll
      for (int j = 0; j < 4; ++j) {
        const int q16 = quad * 4 + j;
        float l = rsL[0][nt][q16] + rsL[1][nt][q16] + rsL[2][nt][q16] + rsL[3][nt][q16];
        const size_t row = (size_t)(b * S_LEN + Q0 + nt * 16 + q16);
        ctx[row * DM + h * DHEAD + w * 16 + l16] = f2bf(acc[j] / l);
      }
    }
  }
}

extern "C" void kernel_launch(void* const* d_in, const int* in_sizes, int n_in,
                              void* d_out, int out_size, void* d_ws, size_t ws_size,
                              hipStream_t stream) {
  const float* Xq = (const float*)d_in[0];
  const float* Xk = (const float*)d_in[1];
  const float* Xv = (const float*)d_in[2];
  const float* Wq = (const float*)d_in[5];
  const float* Wk = (const float*)d_in[6];
  const float* Wv = (const float*)d_in[7];
  const float* Wo = (const float*)d_in[8];
  float* out = (float*)d_out;

  char* ws = (char*)d_ws;
  constexpr size_t XBYTES = (size_t)MROWS * DM * 2;  // 8 MiB
  constexpr size_t WBYTES = (size_t)DM * DM * 2;     // 2 MiB
  unsigned short* xq_bf = (unsigned short*)(ws);
  unsigned short* xk_bf = (unsigned short*)(ws + XBYTES);
  unsigned short* xv_bf = (unsigned short*)(ws + 2 * XBYTES);
  unsigned short* wqt   = (unsigned short*)(ws + 3 * XBYTES);
  unsigned short* wkt   = (unsigned short*)(ws + 3 * XBYTES + WBYTES);
  unsigned short* wvt   = (unsigned short*)(ws + 3 * XBYTES + 2 * WBYTES);
  unsigned short* wot   = (unsigned short*)(ws + 3 * XBYTES + 3 * WBYTES);
  unsigned short* qp    = (unsigned short*)(ws + 3 * XBYTES + 4 * WBYTES);
  unsigned short* kp    = (unsigned short*)(ws + 4 * XBYTES + 4 * WBYTES);
  unsigned short* vt    = (unsigned short*)(ws + 5 * XBYTES + 4 * WBYTES); // V^T, written by V-GEMM
  unsigned short* ctx   = xq_bf;  // dead after Q projection

  // fused prep: y=0..2 convert Xq/Xk/Xv; y=3 transpose the 4 weights
  prep_kernel<<<dim3(4096, 4), 256, 0, stream>>>(Xq, Xk, Xv, xq_bf, xk_bf, xv_bf,
                                                 Wq, Wk, Wv, Wo, wqt, wkt, wvt, wot);

  gemm_qkv<<<dim3(DM / 128, MROWS / 128, 3), 256, 0, stream>>>(
      xq_bf, xk_bf, xv_bf, wqt, wkt, wvt, qp, kp, vt);

  // paired causal schedule + XCD remap: block lin -> (bh with bh%8==lin%8, pair)
  // => all 16 pair-blocks of a bh on one XCD; uniform 33 steps each; 512 blocks.
  attn_kernel<<<dim3(16, BATCH * NHEAD), 256, 0, stream>>>(qp, kp, vt, ctx);

  gemm_out64<<<dim3(DM / 128, MROWS / 64), 256, 0, stream>>>(ctx, wot, out);
}